// Round 10
// baseline (951.216 us; speedup 1.0000x reference)
//
#include <hip/hip_runtime.h>
#include <math.h>

// ---------------------------------------------------------------------------
// SwinTransformerBlock3D  (B=2, D=16, H=56, W=56, C=256, heads=8, ws=4, ss=2)
// f32 in / f32 out. M = 100352 rows, 1568 windows. 7 launches:
//   transpose_all -> ln1+roll+partition -> qkv GEMM (head-major out) -> attn
//   -> proj GEMM(+reverse+roll+resid -> d_out f32) -> ln2 -> fused MLP v2
// History: R4 (WIN 734->706) LDS-bounce epilogue. R5 mlp fusion FAILED (332us;
//   76 vmcnt(0)-drain barriers from W staging + 40KB/152VGPR shape).
//   R6 (WIN 706->667) 2-phase dbuf. R7/R8 window fusion failed. R9 (WIN
//   667->660) head-major qkv -> coalesced attn loads; fc1 XCD swizzle cut
//   FETCH 201->27MB with dur UNCHANGED -> fc1/fc2 are issue-bound, not
//   fetch-bound (VALU 65%, Mfma 17.7%, HBM 1.9TB/s).
// Round 10: mlp2_k — fc1+GELU+fc2 fused with R5's failure mechanisms fixed:
//   (a) W1/W2 frag-packed (R8-proven layout), read coalesced DIRECTLY from
//       L2 -> zero W-staging barriers; (b) ~19 barriers/block total with
//   64 MFMA between each; (c) 48KB LDS -> 3 blocks/CU, launch_bounds(256,3).
//   Kills the 410MB h1 HBM round-trip. Floors: HBM 41us, MFMA 42us.
// ---------------------------------------------------------------------------

using f32x4  = __attribute__((ext_vector_type(4))) float;
using bf16x8 = __attribute__((ext_vector_type(8))) short;

#define MFMA16 __builtin_amdgcn_mfma_f32_16x16x32_bf16

__device__ __forceinline__ short f2bf(float f) {
  unsigned u = __builtin_bit_cast(unsigned, f);
  u += 0x7fffu + ((u >> 16) & 1u);          // RNE
  return (short)(u >> 16);
}

__device__ __forceinline__ float gelu_f(float v) {
  const float u = 1.5957691216057308f * v * (1.f + 0.044715f * v * v);
  const float e = __expf(u);
  return v - v * __builtin_amdgcn_rcpf(e + 1.f);
}

#define GLDS16(g, l) __builtin_amdgcn_global_load_lds(                        \
    (__attribute__((address_space(1))) void*)(g),                             \
    (__attribute__((address_space(3))) void*)(l), 16, 0, 0)

// ---------------------------------------------------------------------------
// weight prep (1280 blocks):
//   qkv/proj: [K][N] f32 -> [N][K] bf16 (gemm_k staging)
//   fc1/fc2: MFMA-fragment pack: frag[((ct*KT + kt)*64 + lane)*8 + j] =
//            W[kt*32 + (lane>>4)*8 + j][ct*16 + (lane&15)]
__global__ void transpose_all_k(const float* __restrict__ qkv_w,
                                const float* __restrict__ proj_w,
                                const float* __restrict__ fc1_w,
                                const float* __restrict__ fc2_w,
                                short* __restrict__ o_qkv,
                                short* __restrict__ o_proj,
                                short* __restrict__ o_fc1,
                                short* __restrict__ o_fc2) {
  const int bid = blockIdx.x;
  if (bid < 768) {                        // qkv: [256][768] -> [768][256]
    const int idx = bid * 256 + threadIdx.x;
    const int k = idx / 768, n = idx % 768;
    o_qkv[(size_t)n * 256 + k] = f2bf(qkv_w[idx]);
  } else if (bid < 1024) {                // proj: [256][256] -> [256][256]
    const int idx = (bid - 768) * 256 + threadIdx.x;
    const int k = idx >> 8, n = idx & 255;
    o_proj[(size_t)n * 256 + k] = f2bf(proj_w[idx]);
  } else if (bid < 1152) {                // fc1 frag-pack: ct 0..63, kt 0..7
    const int idx = (bid - 1024) * 256 + threadIdx.x;   // 0..32767
    const int lane = idx & 63, rest = idx >> 6;
    const int kt = rest & 7, ct = rest >> 3;
    const int kb = kt * 32 + (lane >> 4) * 8;
    const int n = ct * 16 + (lane & 15);
    bf16x8 o;
#pragma unroll
    for (int j = 0; j < 8; ++j)
      o[j] = f2bf(fc1_w[(size_t)(kb + j) * 1024 + n]);
    *(bf16x8*)(o_fc1 + (size_t)idx * 8) = o;
  } else {                                // fc2 frag-pack: ct 0..15, kt 0..31
    const int idx = (bid - 1152) * 256 + threadIdx.x;   // 0..32767
    const int lane = idx & 63, rest = idx >> 6;
    const int kt = rest & 31, ct = rest >> 5;
    const int kb = kt * 32 + (lane >> 4) * 8;
    const int n = ct * 16 + (lane & 15);
    bf16x8 o;
#pragma unroll
    for (int j = 0; j < 8; ++j)
      o[j] = f2bf(fc2_w[(size_t)(kb + j) * 256 + n]);
    *(bf16x8*)(o_fc2 + (size_t)idx * 8) = o;
  }
}

// ---------------------------------------------------------------------------
// LN1 + roll(-2) + window partition.  One wave per output row.
__global__ __launch_bounds__(256) void ln1_part_k(
    const float* __restrict__ x, const float* __restrict__ g,
    const float* __restrict__ bta, short* __restrict__ xw) {
  const int wave = threadIdx.x >> 6, lane = threadIdx.x & 63;
  const int row = blockIdx.x * 4 + wave;
  const int win = row >> 6, tok = row & 63;
  const int b = win / 784, wi = win % 784;
  const int wd = wi / 196, wh = (wi / 14) % 14, ww = wi % 14;
  const int tz = tok >> 4, ty = (tok >> 2) & 3, tx = tok & 3;
  const int gd = (wd * 4 + tz + 2) & 15;
  int gh = wh * 4 + ty + 2; if (gh >= 56) gh -= 56;
  int gw = ww * 4 + tx + 2; if (gw >= 56) gw -= 56;
  const size_t src = ((((size_t)b * 16 + gd) * 56 + gh) * 56 + gw) * 256;
  const float4 v = ((const float4*)(x + src))[lane];
  float s = v.x + v.y + v.z + v.w;
#pragma unroll
  for (int m = 1; m < 64; m <<= 1) s += __shfl_xor(s, m);
  const float mean = s * (1.f / 256.f);
  const float dx = v.x - mean, dy = v.y - mean, dz = v.z - mean, dw = v.w - mean;
  float q = dx * dx + dy * dy + dz * dz + dw * dw;
#pragma unroll
  for (int m = 1; m < 64; m <<= 1) q += __shfl_xor(q, m);
  const float rstd = rsqrtf(q * (1.f / 256.f) + 1e-5f);
  const float4 gg = ((const float4*)g)[lane];
  const float4 bb = ((const float4*)bta)[lane];
  short4 o;
  o.x = f2bf(dx * rstd * gg.x + bb.x);
  o.y = f2bf(dy * rstd * gg.y + bb.y);
  o.z = f2bf(dz * rstd * gg.z + bb.z);
  o.w = f2bf(dw * rstd * gg.w + bb.w);
  *(short4*)(xw + (size_t)row * 256 + lane * 4) = o;
}

// LN2: reads f32 x1 (== d_out), writes bf16 yn
__global__ __launch_bounds__(256) void ln2_k(
    const float* __restrict__ x1, const float* __restrict__ g,
    const float* __restrict__ bta, short* __restrict__ yn) {
  const int wave = threadIdx.x >> 6, lane = threadIdx.x & 63;
  const int row = blockIdx.x * 4 + wave;
  const float4 v = ((const float4*)(x1 + (size_t)row * 256))[lane];
  float s = v.x + v.y + v.z + v.w;
#pragma unroll
  for (int m = 1; m < 64; m <<= 1) s += __shfl_xor(s, m);
  const float mean = s * (1.f / 256.f);
  const float dx = v.x - mean, dy = v.y - mean, dz = v.z - mean, dw = v.w - mean;
  float q = dx * dx + dy * dy + dz * dz + dw * dw;
#pragma unroll
  for (int m = 1; m < 64; m <<= 1) q += __shfl_xor(q, m);
  const float rstd = rsqrtf(q * (1.f / 256.f) + 1e-5f);
  const float4 gg = ((const float4*)g)[lane];
  const float4 bb = ((const float4*)bta)[lane];
  short4 o;
  o.x = f2bf(dx * rstd * gg.x + bb.x);
  o.y = f2bf(dy * rstd * gg.y + bb.y);
  o.z = f2bf(dz * rstd * gg.z + bb.z);
  o.w = f2bf(dw * rstd * gg.w + bb.w);
  *(short4*)(yn + (size_t)row * 256 + lane * 4) = o;
}

// ---------------------------------------------------------------------------
// bf16 MFMA GEMM: C[M,N] = A[M,K] * Bt[N,K]^T + bias. 128x128 tile, BK=64,
// glds16 + XOR swizzle, 2-phase dbuf K-loop, LDS-bounce epilogue.
// EPI: 0=bf16 store in HEAD-MAJOR qkv layout [win][h][gq][64][32]
//      2=f32 swin-reverse+roll+resid(x f32) scatter -> d_out
template <int EPI, int XSWZ>
__global__ __launch_bounds__(256) void gemm_k(
    const short* __restrict__ A, const short* __restrict__ Bt,
    const float* __restrict__ bias, const float* __restrict__ resid,
    void* __restrict__ OutP, int N, int K) {
  __shared__ short SMEM[32768];               // 64 KB: buf b at b*16384
  const int tid = threadIdx.x;
  const int wave = tid >> 6, lane = tid & 63;
  const int quad = lane >> 4, l15 = lane & 15;
  int m0, n0;
  if constexpr (XSWZ) {
    const int gx = gridDim.x;
    int lin = blockIdx.y * gx + blockIdx.x;
    const int q8 = (gx * gridDim.y) >> 3;
    lin = (lin & 7) * q8 + (lin >> 3);
    m0 = (lin / gx) * 128;
    n0 = (lin % gx) * 128;
  } else {
    m0 = blockIdx.y * 128;
    n0 = blockIdx.x * 128;
  }
  const int wm = (wave >> 1) * 64, wn = (wave & 1) * 64;

  f32x4 acc[4][4] = {};

  auto stage = [&](int b, int kk) {
    short* Asb = SMEM + b * 16384;
    short* Bsb = Asb + 8192;
#pragma unroll
    for (int i = 0; i < 4; ++i) {
      const int p = wave * 256 + i * 64 + lane;
      const int row = p >> 3;
      const int c = (p & 7) ^ (row & 7);
      GLDS16(A  + (size_t)(m0 + row) * K + (kk + c * 8),
             Asb + (size_t)(wave * 256 + i * 64) * 8);
      GLDS16(Bt + (size_t)(n0 + row) * K + (kk + c * 8),
             Bsb + (size_t)(wave * 256 + i * 64) * 8);
    }
  };
  auto compute = [&](int b) {
    const short* Asb = SMEM + b * 16384;
    const short* Bsb = Asb + 8192;
#pragma unroll
    for (int ks = 0; ks < 2; ++ks) {
      bf16x8 af[4], bfr[4];
#pragma unroll
      for (int t = 0; t < 4; ++t) {
        const int ra = wm + t * 16 + l15;
        const int ca = (ks * 4 + quad) ^ (ra & 7);
        af[t] = *(const bf16x8*)(Asb + ra * 64 + ca * 8);
        const int rb = wn + t * 16 + l15;
        const int cb = (ks * 4 + quad) ^ (rb & 7);
        bfr[t] = *(const bf16x8*)(Bsb + rb * 64 + cb * 8);
      }
#pragma unroll
      for (int mt = 0; mt < 4; ++mt)
#pragma unroll
        for (int nt = 0; nt < 4; ++nt)
          acc[mt][nt] = MFMA16(af[mt], bfr[nt], acc[mt][nt], 0, 0, 0);
    }
  };

  stage(0, 0);
  __syncthreads();
  int cur = 0;
  const int NT = K >> 6;
  for (int t = 0; t < NT - 1; ++t) {
    stage(cur ^ 1, (t + 1) * 64);
    compute(cur);
    __syncthreads();
    cur ^= 1;
  }
  compute(cur);

  // --- LDS-bounce epilogue.  acc layout: row=quad*4+reg, col=l15 [m89/m91].
  __syncthreads();
  if constexpr (EPI == 0) {
#pragma unroll
    for (int nt = 0; nt < 4; ++nt) {
      const int col = wn + nt * 16 + l15;
      const float bv = bias[n0 + col];
#pragma unroll
      for (int mt = 0; mt < 4; ++mt)
#pragma unroll
        for (int reg = 0; reg < 4; ++reg) {
          const int row = wm + mt * 16 + quad * 4 + reg;
          const int byte = (row << 8) | ((col << 1) ^ ((row & 7) << 4));
          *(short*)((char*)SMEM + byte) = f2bf(acc[mt][nt][reg] + bv);
        }
    }
    __syncthreads();
    short* out = (short*)OutP;
#pragma unroll
    for (int i = 0; i < 8; ++i) {
      const int off = i * 4096 + tid * 16;    // logical byte in [128][256B]
      const int row = off >> 8;
      const bf16x8 val =
          *(const bf16x8*)((char*)SMEM + (off ^ ((row & 7) << 4)));
      // head-major: [win][h][gq][64][32]
      const int colg = n0 + ((off & 255) >> 1);
      const int gq = colg >> 8, rem = colg & 255;
      const int hh = rem >> 5, dd = rem & 31;
      const int grow = m0 + row;
      const int win = grow >> 6, tok = grow & 63;
      *(bf16x8*)(out + ((((size_t)win * 8 + hh) * 3 + gq) << 11)
                     + tok * 32 + dd) = val;
    }
  } else {
    // f32 path in two 64-row halves (32 KB each): Cs_f32[64][128]
    float* out = (float*)OutP;
#pragma unroll
    for (int hh = 0; hh < 2; ++hh) {
      if (hh) __syncthreads();
      if (wm == hh * 64) {
#pragma unroll
        for (int nt = 0; nt < 4; ++nt) {
          const int col = wn + nt * 16 + l15;
          const float bv = bias[n0 + col];
#pragma unroll
          for (int mt = 0; mt < 4; ++mt)
#pragma unroll
            for (int reg = 0; reg < 4; ++reg) {
              const int rloc = mt * 16 + quad * 4 + reg;
              const int byte = (rloc << 9) | ((col << 2) ^ ((rloc & 7) << 4));
              *(float*)((char*)SMEM + byte) = acc[mt][nt][reg] + bv;
            }
        }
      }
      __syncthreads();
#pragma unroll
      for (int i = 0; i < 8; ++i) {
        const int off = i * 4096 + tid * 16;  // logical byte in [64][512B]
        const int rloc = off >> 9;
        f32x4 val = *(const f32x4*)((char*)SMEM + (off ^ ((rloc & 7) << 4)));
        const int colf = (off & 511) >> 2;
        const int grow = m0 + hh * 64 + rloc;
        const int win = grow >> 6, tok = grow & 63;
        const int b = win / 784, wi = win % 784;
        const int wd = wi / 196, wh = (wi / 14) % 14, ww = wi % 14;
        const int tz = tok >> 4, ty = (tok >> 2) & 3, tx = tok & 3;
        const int gd = (wd * 4 + tz + 2) & 15;
        int gh = wh * 4 + ty + 2; if (gh >= 56) gh -= 56;
        int gw = ww * 4 + tx + 2; if (gw >= 56) gw -= 56;
        const size_t dst = ((((size_t)b * 16 + gd) * 56 + gh) * 56 + gw) * 256
                           + n0 + colf;
        const f32x4 r = *(const f32x4*)(resid + dst);
        val = val + r;
        *(f32x4*)(out + dst) = val;
      }
    }
  }
}

// ---------------------------------------------------------------------------
// Fused MLP v2: out = x1 + GELU(yn @ W1 + b1) @ W2 + b2.
// Block = 64 rows, 4 waves, 1568 blocks. LDS 48KB: As[64][256]bf16 32KB |
// Hs[64][128]bf16 16KB; epilogue reuses As region as Cs f32 [32][256].
// W1/W2 frag-packed, read directly from L2 (no staging, no extra barriers).
// Per j-chunk (8 total): stage1 (0 barriers) -> barrier -> Hs write ->
// barrier -> stage2.  ~19 barriers/block vs R5's 76.
__global__ __launch_bounds__(256, 3) void mlp2_k(
    const short* __restrict__ yn, const short* __restrict__ W1f,
    const short* __restrict__ W2f, const float* __restrict__ b1,
    const float* __restrict__ b2, const float* __restrict__ resid,
    float* __restrict__ out) {
  __shared__ __align__(16) char SM[49152];
  const int tid = threadIdx.x;
  const int wave = tid >> 6, lane = tid & 63;
  const int quad = lane >> 4, l15 = lane & 15;
  const int m0 = blockIdx.x * 64;

  // stage As [64][256] bf16: source-swizzled chunks, linear dest (m173)
#pragma unroll
  for (int i = 0; i < 8; ++i) {
    const int p = i * 256 + tid;
    const int row = p >> 5;
    const int c = (p & 31) ^ (row & 7);
    GLDS16(yn + (size_t)(m0 + row) * 256 + c * 8, SM + p * 16);
  }
  __syncthreads();

  f32x4 oacc[4][4] = {};
  for (int j = 0; j < 8; ++j) {
    // ---- stage-1: hacc[4][2] = As(64x256) @ W1-slice(256x32/wave)
    f32x4 hacc[4][2] = {};
#pragma unroll
    for (int kk = 0; kk < 8; ++kk) {
      bf16x8 af[4];
#pragma unroll
      for (int mt = 0; mt < 4; ++mt) {
        const int t = mt * 16 + l15;
        af[mt] = *(const bf16x8*)(
            SM + t * 512 + (((kk * 4 + quad) ^ (t & 7)) << 4));
      }
#pragma unroll
      for (int ct = 0; ct < 2; ++ct) {
        const int ctg = j * 8 + wave * 2 + ct;
        const bf16x8 w1 = *(const bf16x8*)(
            W1f + (size_t)((ctg * 8 + kk) * 64 + lane) * 8);
#pragma unroll
        for (int mt = 0; mt < 4; ++mt)
          hacc[mt][ct] = MFMA16(af[mt], w1, hacc[mt][ct], 0, 0, 0);
      }
    }
    // ---- GELU -> Hs (barrier: prior stage-2 readers of Hs done)
    if (j) __syncthreads();
#pragma unroll
    for (int ct = 0; ct < 2; ++ct) {
      const int hc = wave * 32 + ct * 16 + l15;        // 0..127
      const float bv = b1[j * 128 + hc];
#pragma unroll
      for (int mt = 0; mt < 4; ++mt)
#pragma unroll
        for (int reg = 0; reg < 4; ++reg) {
          const int row = mt * 16 + quad * 4 + reg;
          const float v = gelu_f(hacc[mt][ct][reg] + bv);
          const int byte =
              32768 + row * 256 + (((hc >> 3) ^ (row & 7)) << 4) + (hc & 7) * 2;
          *(short*)(SM + byte) = f2bf(v);
        }
    }
    __syncthreads();                                   // Hs visible
    // ---- stage-2: oacc += Hs(64x128) @ W2-slice(128x64/wave)
#pragma unroll
    for (int kk2 = 0; kk2 < 4; ++kk2) {
      bf16x8 ah[4];
#pragma unroll
      for (int mt = 0; mt < 4; ++mt) {
        const int t = mt * 16 + l15;
        ah[mt] = *(const bf16x8*)(
            SM + 32768 + t * 256 + (((kk2 * 4 + quad) ^ (t & 7)) << 4));
      }
#pragma unroll
      for (int nt = 0; nt < 4; ++nt) {
        const int ct2 = wave * 4 + nt;
        const bf16x8 w2 = *(const bf16x8*)(
            W2f + (size_t)((ct2 * 32 + j * 4 + kk2) * 64 + lane) * 8);
#pragma unroll
        for (int mt = 0; mt < 4; ++mt)
          oacc[mt][nt] = MFMA16(ah[mt], w2, oacc[mt][nt], 0, 0, 0);
      }
    }
  }

  // ---- epilogue (R5-proven shape): two 32-row halves via Cs f32 [32][256]
#pragma unroll
  for (int hh = 0; hh < 2; ++hh) {
    __syncthreads();
#pragma unroll
    for (int mi = 0; mi < 2; ++mi) {
      const int mt = hh * 2 + mi;
#pragma unroll
      for (int nt = 0; nt < 4; ++nt) {
        const int col = wave * 64 + nt * 16 + l15;
        const float bv = b2[col];
#pragma unroll
        for (int reg = 0; reg < 4; ++reg) {
          const int rl = mi * 16 + quad * 4 + reg;
          const int byte =
              rl * 1024 + (((col >> 2) ^ (rl & 7)) << 4) + (col & 3) * 4;
          *(float*)(SM + byte) = oacc[mt][nt][reg] + bv;
        }
      }
    }
    __syncthreads();
#pragma unroll
    for (int i = 0; i < 8; ++i) {
      const int off = i * 4096 + tid * 16;             // [32][1024B]
      const int rloc = off >> 10, w = off & 1023;
      const int byte = rloc * 1024 + (((w >> 4) ^ (rloc & 7)) << 4);
      f32x4 v = *(const f32x4*)(SM + byte);
      const size_t dst = (size_t)(m0 + hh * 32 + rloc) * 256 + (w >> 2);
      const f32x4 r = *(const f32x4*)(resid + dst);
      v = v + r;
      *(f32x4*)(out + dst) = v;
    }
  }
}

// ---------------------------------------------------------------------------
// Windowed attention. grid = 1568*2 blocks; 4 waves, 1 head/wave.
// qkv head-major [win][h][q/k/v][64][32]: Q/K fragment loads coalesced.
__global__ __launch_bounds__(256) void attn_k(
    const short* __restrict__ qkv, const float* __restrict__ rpb,
    short* __restrict__ aout) {
  __shared__ short Plds[4 * 64 * 80];
  const int tid = threadIdx.x;
  const int wave = tid >> 6, lane = tid & 63;
  const int quad = lane >> 4, l15 = lane & 15;
  const int win = blockIdx.x >> 1;
  const int h = ((blockIdx.x & 1) << 2) + wave;
  const int wi = win % 784;
  const int wd = wi / 196, wh = (wi / 14) % 14, ww = wi % 14;
  const short* base = qkv + ((((size_t)win * 8 + h) * 3) << 11);

  bf16x8 qf[4], kf[4];
#pragma unroll
  for (int t = 0; t < 4; ++t) {
    qf[t] = *(const bf16x8*)(base + (t * 16 + l15) * 32 + quad * 8);
    kf[t] = *(const bf16x8*)(base + 2048 + (t * 16 + l15) * 32 + quad * 8);
  }
  f32x4 S[4][4] = {};
#pragma unroll
  for (int mt = 0; mt < 4; ++mt)
#pragma unroll
    for (int nt = 0; nt < 4; ++nt)
      S[mt][nt] = MFMA16(qf[mt], kf[nt], S[mt][nt], 0, 0, 0);

  const bool bd = (wd == 3), bh = (wh == 13), bw = (ww == 13);
  const int yc = l15 >> 2, xc = l15 & 3;
  int labc[4];
#pragma unroll
  for (int nt = 0; nt < 4; ++nt) {
    const int rd = bd ? (nt < 2 ? 1 : 2) : 0;
    const int rh = bh ? (yc < 2 ? 1 : 2) : 0;
    const int rw = bw ? (xc < 2 ? 1 : 2) : 0;
    labc[nt] = rd * 9 + rh * 3 + rw;
  }
  const float scale = 0.17677669529663687f;   // 32^-0.5
#pragma unroll
  for (int mt = 0; mt < 4; ++mt) {
    const int rdr = bd ? (mt < 2 ? 1 : 2) : 0;
    const int rhr = bh ? (quad < 2 ? 1 : 2) : 0;
#pragma unroll
    for (int reg = 0; reg < 4; ++reg) {
      const int rwr = bw ? (reg < 2 ? 1 : 2) : 0;
      const int labr = rdr * 9 + rhr * 3 + rwr;
      float sc[4];
#pragma unroll
      for (int nt = 0; nt < 4; ++nt) {
        const int rpi = (mt - nt + 3) * 49 + (quad - yc + 3) * 7 + (reg - xc + 3);
        const float bias = rpb[rpi * 8 + h];
        const float mv = (labr == labc[nt]) ? 0.f : -100.f;
        sc[nt] = S[mt][nt][reg] * scale + bias + mv;
      }
      float mx = fmaxf(fmaxf(sc[0], sc[1]), fmaxf(sc[2], sc[3]));
      mx = fmaxf(mx, __shfl_xor(mx, 1));
      mx = fmaxf(mx, __shfl_xor(mx, 2));
      mx = fmaxf(mx, __shfl_xor(mx, 4));
      mx = fmaxf(mx, __shfl_xor(mx, 8));
      float p[4], sum = 0.f;
#pragma unroll
      for (int nt = 0; nt < 4; ++nt) { p[nt] = __expf(sc[nt] - mx); sum += p[nt]; }
      sum += __shfl_xor(sum, 1);
      sum += __shfl_xor(sum, 2);
      sum += __shfl_xor(sum, 4);
      sum += __shfl_xor(sum, 8);
      const float inv = 1.f / sum;
      const int r = mt * 16 + quad * 4 + reg;
#pragma unroll
      for (int nt = 0; nt < 4; ++nt)
        Plds[(wave * 64 + r) * 80 + nt * 16 + l15] = f2bf(p[nt] * inv);
    }
  }

  bf16x8 vf[2][2];
#pragma unroll
  for (int kt = 0; kt < 2; ++kt)
#pragma unroll
    for (int n2 = 0; n2 < 2; ++n2)
#pragma unroll
      for (int j = 0; j < 8; ++j)
        vf[kt][n2][j] =
            base[4096 + (kt * 32 + quad * 8 + j) * 32 + n2 * 16 + l15];

  f32x4 O[4][2] = {};
#pragma unroll
  for (int mt = 0; mt < 4; ++mt) {
    const short* pr = &Plds[(wave * 64 + mt * 16 + l15) * 80 + quad * 8];
    const bf16x8 pa0 = *(const bf16x8*)pr;
    const bf16x8 pa1 = *(const bf16x8*)(pr + 32);
#pragma unroll
    for (int n2 = 0; n2 < 2; ++n2) {
      O[mt][n2] = MFMA16(pa0, vf[0][n2], O[mt][n2], 0, 0, 0);
      O[mt][n2] = MFMA16(pa1, vf[1][n2], O[mt][n2], 0, 0, 0);
    }
  }
#pragma unroll
  for (int mt = 0; mt < 4; ++mt)
#pragma unroll
    for (int n2 = 0; n2 < 2; ++n2)
#pragma unroll
      for (int reg = 0; reg < 4; ++reg) {
        const int tok = mt * 16 + quad * 4 + reg;
        aout[((size_t)win * 64 + tok) * 256 + h * 32 + n2 * 16 + l15] =
            f2bf(O[mt][n2][reg]);
      }
}

// ---------------------------------------------------------------------------
extern "C" void kernel_launch(void* const* d_in, const int* in_sizes, int n_in,
                              void* d_out, int out_size, void* d_ws,
                              size_t ws_size, hipStream_t stream) {
  const float* x      = (const float*)d_in[0];
  const float* n1g    = (const float*)d_in[1];
  const float* n1b    = (const float*)d_in[2];
  const float* qkv_w  = (const float*)d_in[3];
  const float* qkv_b  = (const float*)d_in[4];
  const float* proj_w = (const float*)d_in[5];
  const float* proj_b = (const float*)d_in[6];
  const float* rpb    = (const float*)d_in[7];
  const float* n2g    = (const float*)d_in[8];
  const float* n2b    = (const float*)d_in[9];
  const float* fc1_w  = (const float*)d_in[10];
  const float* fc1_b  = (const float*)d_in[11];
  const float* fc2_w  = (const float*)d_in[12];
  const float* fc2_b  = (const float*)d_in[13];

  char* ws = (char*)d_ws;
  short* wt_qkv  = (short*)(ws + 0);          //     393,216 B
  short* wt_proj = (short*)(ws + 393216);     //     131,072 B
  short* wt_fc1  = (short*)(ws + 524288);     //     524,288 B (frag-packed)
  short* wt_fc2  = (short*)(ws + 1048576);    //     524,288 B (frag-packed)
  short* bufS    = (short*)(ws + 1572864);    //  51,380,224 B (xw/ao/yn)
  short* bufL    = (short*)(ws + 52953088);   // 205,520,896 B (qkv head-major)
  // total 258,473,984 B
  float* x1      = (float*)d_out;             // x1 lives in d_out (f32)

  transpose_all_k<<<1280, 256, 0, stream>>>(qkv_w, proj_w, fc1_w, fc2_w,
                                            wt_qkv, wt_proj, wt_fc1, wt_fc2);
  ln1_part_k<<<25088, 256, 0, stream>>>(x, n1g, n1b, bufS);
  gemm_k<0, 0><<<dim3(6, 784), 256, 0, stream>>>(bufS, wt_qkv, qkv_b, nullptr,
                                                 bufL, 768, 256);
  attn_k<<<3136, 256, 0, stream>>>(bufL, rpb, bufS);
  gemm_k<2, 0><<<dim3(2, 784), 256, 0, stream>>>(bufS, wt_proj, proj_b, x,
                                                 x1, 256, 256);
  ln2_k<<<25088, 256, 0, stream>>>(x1, n2g, n2b, bufS);
  mlp2_k<<<1568, 256, 0, stream>>>(bufS, wt_fc1, wt_fc2, fc1_b, fc2_b,
                                   x1, x1);
}